// Round 6
// baseline (329.148 us; speedup 1.0000x reference)
//
#include <hip/hip_runtime.h>

// GAT 2-layer forward on MI355X.
// Round 16: build-phase occupancy attack + agg csr software-pipeline.
// Accounting: aggs ~97 + gemm1f ~12 leave ~210us in build dispatches that sit
// just under the 52us top-5 threshold. bucket_rp_sort runs 391 blocks x 256thr
// with 51KB LDS = 1.5 blocks/CU (~12 waves/CU, half the GPU idle);
// chunk_scatter_sorted 36KB LDS at 256thr = 16 waves/CU.
//  - both -> 512 threads/block: rp_sort 24 waves/CU + per-thread edges halved
//    (33->16.5); scatter 32 waves/CU (8 edges/thread staged).
//  - agg1_attn/agg2_gemm: prefetch next 4-edge group's csr indices while the
//    current group's as/h1h gathers are in flight (removes csr latency from
//    the steady-state dependence chain). +4 VGPR, stays within (256,8).
// bucket_hist/bucket_scan/gemm1f and all layouts unchanged from r15.

#define DEVFN __device__ __forceinline__
#define CB_SHIFT 8
#define CB_SZ 256
#define SC_CHUNK 4096
#define NBMAX 512    // max buckets supported (N <= 131072)
#define STASH 12288  // bucket stash entries (mean ~8.5k)

DEVFN unsigned short f2h(float f) {
  _Float16 h = (_Float16)f;
  unsigned short u;
  __builtin_memcpy(&u, &h, 2);
  return u;
}
DEVFN float h2f(unsigned short u) {
  _Float16 h;
  __builtin_memcpy(&h, &u, 2);
  return (float)h;
}

DEVFN float lrelu(float e) { return e > 0.f ? e : 0.2f * e; }

DEVFN void acc8(float* acc, float x, uint4 u) {
  acc[0] = fmaf(x, h2f(u.x & 0xffff), acc[0]);
  acc[1] = fmaf(x, h2f(u.x >> 16),    acc[1]);
  acc[2] = fmaf(x, h2f(u.y & 0xffff), acc[2]);
  acc[3] = fmaf(x, h2f(u.y >> 16),    acc[3]);
  acc[4] = fmaf(x, h2f(u.z & 0xffff), acc[4]);
  acc[5] = fmaf(x, h2f(u.z >> 16),    acc[5]);
  acc[6] = fmaf(x, h2f(u.w & 0xffff), acc[6]);
  acc[7] = fmaf(x, h2f(u.w >> 16),    acc[7]);
}

DEVFN void read_edge(const long long* eg64, const int* eg32, int is64, int E,
                     int i, int& s, int& d) {
  if (i >= E) { s = d = i - E; return; }
  if (is64) { s = (int)eg64[i]; d = (int)eg64[E + i]; }
  else      { s = eg32[i];      d = eg32[E + i]; }
}

// block-uniform edge dtype detection: EVERY wave samples the same 64 in-range
// indices (int64 data => high words all zero; int32 data => random src values).
DEVFN int detect64(const int* eg32, int E, int i0, int t) {
  int base = i0;
  if (base > E - 64) base = E - 64;
  if (base < 0) base = 0;
  int i = base + (t & 63);
  unsigned long long m = __ballot((i < E) && (eg32[2 * i + 1] != 0));
  return m == 0ull;
}

// ---------------- CSR build, stage 1: global bucket histogram ----------------
__global__ __launch_bounds__(256) void bucket_hist(const long long* eg64,
                                                   const int* eg32,
                                                   int E, int N, int NB2,
                                                   int* __restrict__ bhist) {
  __shared__ int lh[NBMAX];
  int t = threadIdx.x;
  lh[t] = 0; lh[t + 256] = 0;
  int is64 = detect64(eg32, E, 0, t);
  __syncthreads();
  int EN = E + N;
  int step = (int)gridDim.x * 1024;
  for (int base = (int)blockIdx.x * 1024; base < EN; base += step) {
#pragma unroll
    for (int k = 0; k < 4; k++) {
      int i = base + k * 256 + t;
      if (i < EN) {
        int d;
        if (i >= E) d = i - E;
        else d = is64 ? (int)eg64[E + i] : eg32[E + i];
        atomicAdd(&lh[d >> CB_SHIFT], 1);
      }
    }
  }
  __syncthreads();
  if (t < NB2 && lh[t]) atomicAdd(&bhist[t], lh[t]);
  int t2 = t + 256;
  if (t2 < NB2 && lh[t2]) atomicAdd(&bhist[t2], lh[t2]);
}

// stage 2: single-block scan over NB2 bucket counts -> bscan (excl) + gcur
__global__ void bucket_scan(const int* __restrict__ bhist,
                            int* __restrict__ bscan, int* __restrict__ gcur,
                            int NB2, int EN) {
  __shared__ int buf[2][NBMAX];
  int t = threadIdx.x;  // 512 threads
  int v = (t < NB2) ? bhist[t] : 0;
  buf[0][t] = v;
  __syncthreads();
  int pin = 0;
  for (int off = 1; off < NBMAX; off <<= 1) {
    int nv = buf[pin][t] + (t >= off ? buf[pin][t - off] : 0);
    buf[1 - pin][t] = nv;
    pin ^= 1;
    __syncthreads();
  }
  int excl = buf[pin][t] - v;
  if (t < NB2) { bscan[t] = excl; gcur[t] = excl; }
  if (t == NB2) bscan[t] = EN;
}

// stage 3: sorted scatter, 512 threads (8 edges/thread). Stage chunk in regs,
// counting-sort by bucket in LDS, reserve runs with one atomicAdd per
// (block,bucket), burst-write runs. 36KB LDS -> 4 blocks/CU = 32 waves/CU.
__global__ __launch_bounds__(512) void chunk_scatter_sorted(
    const long long* eg64, const int* eg32, int E, int N, int NB2,
    int* __restrict__ gcur, int* __restrict__ tmp) {
  __shared__ int lh[NBMAX];
  __shared__ int lscan[NBMAX];
  __shared__ int lpos[NBMAX];
  __shared__ int gbase[NBMAX];
  __shared__ int sbuf[2][NBMAX];
  __shared__ int payl[SC_CHUNK];
  __shared__ unsigned short bktid[SC_CHUNK];
  int t = threadIdx.x;
  int i0 = (int)blockIdx.x * SC_CHUNK;
  int is64 = detect64(eg32, E, i0, t);
  lh[t] = 0;
  __syncthreads();
  int EN = E + N;
  int i1 = i0 + SC_CHUNK; if (i1 > EN) i1 = EN;
  int total = i1 - i0;
  // load 8 edges/thread into regs (static indexing; d=-1 marks invalid)
  int es[8], ed[8];
#pragma unroll
  for (int bb = 0; bb < 2; bb++) {
#pragma unroll
    for (int k = 0; k < 4; k++) {
      int idx = bb * 4 + k;
      int i = i0 + bb * 2048 + k * 512 + t;
      int s = 0, d = -1;
      if (i < i1) read_edge(eg64, eg32, is64, E, i, s, d);
      es[idx] = s; ed[idx] = d;
    }
  }
  // count
#pragma unroll
  for (int j = 0; j < 8; j++)
    if (ed[j] >= 0) atomicAdd(&lh[ed[j] >> CB_SHIFT], 1);
  __syncthreads();
  // inclusive scan of 512 counters (Hillis-Steele, 1 slot/thread, dbuf)
  sbuf[0][t] = lh[t];
  __syncthreads();
  int pin = 0;
  for (int off = 1; off < NBMAX; off <<= 1) {
    int nv = sbuf[pin][t] + (t >= off ? sbuf[pin][t - off] : 0);
    sbuf[1 - pin][t] = nv;
    pin ^= 1;
    __syncthreads();
  }
  lscan[t] = sbuf[pin][t] - lh[t];
  lpos[t] = lscan[t];
  // reserve global runs (one atomic per non-empty bucket in this chunk)
  if (t < NB2 && lh[t]) gbase[t] = atomicAdd(&gcur[t], lh[t]);
  __syncthreads();
  // place into bucket-grouped LDS order
#pragma unroll
  for (int j = 0; j < 8; j++) {
    if (ed[j] >= 0) {
      int b = ed[j] >> CB_SHIFT;
      int sl = atomicAdd(&lpos[b], 1);
      payl[sl] = (es[j] << CB_SHIFT) | (ed[j] & (CB_SZ - 1));
      bktid[sl] = (unsigned short)b;
    }
  }
  __syncthreads();
  // burst-write runs: consecutive threads -> consecutive addresses per run
  for (int j = t; j < total; j += 512) {
    int b = bktid[j];
    tmp[gbase[b] + (j - lscan[b])] = payl[j];
  }
}

// stage 4: per-bucket (256 nodes) node counts + in-LDS scan -> rp; scatter
// tmp -> csr. 512 threads (16.5 edges/thread); 51KB LDS -> 3 blocks/CU.
__global__ __launch_bounds__(512) void bucket_rp_sort(const int* __restrict__ bscan,
                                                      const int* __restrict__ tmp,
                                                      int* __restrict__ rp,
                                                      int* __restrict__ csr,
                                                      int N, int EN) {
  __shared__ int lc[CB_SZ];
  __shared__ int ps[CB_SZ];
  __shared__ int lcur[CB_SZ];
  __shared__ int stash[STASH];
  int b = blockIdx.x, t = threadIdx.x;
  if (t < CB_SZ) lc[t] = 0;
  __syncthreads();
  int w0 = bscan[b];
  int w1 = bscan[b + 1];
  int cnt = w1 - w0;
  bool fit = (cnt <= STASH);
  // pass 1: count (+stash), 4-stride MLP + predicated 3-wide tail
  int p = w0 + t;
  for (; p + 1536 < w1; p += 2048) {
    int e0 = tmp[p], e1 = tmp[p + 512], e2 = tmp[p + 1024], e3 = tmp[p + 1536];
    if (fit) {
      stash[p - w0] = e0; stash[p - w0 + 512] = e1;
      stash[p - w0 + 1024] = e2; stash[p - w0 + 1536] = e3;
    }
    atomicAdd(&lc[e0 & (CB_SZ - 1)], 1);
    atomicAdd(&lc[e1 & (CB_SZ - 1)], 1);
    atomicAdd(&lc[e2 & (CB_SZ - 1)], 1);
    atomicAdd(&lc[e3 & (CB_SZ - 1)], 1);
  }
  if (p < w1) {
    bool v1 = p + 512 < w1, v2 = p + 1024 < w1;
    int q1 = v1 ? p + 512 : p;
    int q2 = v2 ? p + 1024 : p;
    int e0 = tmp[p], e1 = tmp[q1], e2 = tmp[q2];
    if (fit) {
      stash[p - w0] = e0;
      if (v1) stash[q1 - w0] = e1;
      if (v2) stash[q2 - w0] = e2;
    }
    atomicAdd(&lc[e0 & (CB_SZ - 1)], 1);
    if (v1) atomicAdd(&lc[e1 & (CB_SZ - 1)], 1);
    if (v2) atomicAdd(&lc[e2 & (CB_SZ - 1)], 1);
  }
  __syncthreads();
  int a = 0;
  if (t < CB_SZ) { a = lc[t]; ps[t] = a; }
  __syncthreads();
  for (int off = 1; off < 256; off <<= 1) {
    int v = 0, u = 0;
    if (t < CB_SZ) { v = ps[t]; u = (t >= off) ? ps[t - off] : 0; }
    __syncthreads();
    if (t < CB_SZ) ps[t] = v + u;
    __syncthreads();
  }
  if (t < CB_SZ) {
    int base = w0 + ps[t] - a;  // exclusive prefix within bucket
    lcur[t] = base;
    int n0 = b * CB_SZ;
    if (n0 + t < N) rp[n0 + t] = base;
  }
  if (b == (int)gridDim.x - 1 && t == 0) rp[N] = EN;
  __syncthreads();
  // pass 2: scatter from stash (or global fallback)
  if (fit) {
    for (int j = t; j < cnt; j += 512) {
      int e = stash[j];
      int pos = atomicAdd(&lcur[e & (CB_SZ - 1)], 1);
      csr[pos] = e >> CB_SHIFT;
    }
  } else {
    for (int q = w0 + t; q < w1; q += 512) {
      int e = tmp[q];
      int pos = atomicAdd(&lcur[e & (CB_SZ - 1)], 1);
      csr[pos] = e >> CB_SHIFT;
    }
  }
}

// ---------------- fused GEMM + attn + fp16 pack, layer 1 ----------------
__global__ __launch_bounds__(256) void gemm1f(const float* __restrict__ X,
                                              const float* __restrict__ W,
                                              const float* __restrict__ att_s,
                                              const float* __restrict__ att_d,
                                              uint4* __restrict__ h1h,
                                              float* __restrict__ as1,
                                              float* __restrict__ ad1, int N) {
  __shared__ float Wl[128 * 32];
  __shared__ float Asl[32], Adl[32];
  int t = threadIdx.x;
  for (int i = t; i < 1024; i += 256)
    ((float4*)Wl)[i] = ((const float4*)W)[i];
  if (t < 32) { Asl[t] = att_s[t]; Adl[t] = att_d[t]; }
  __syncthreads();
  int n = blockIdx.x * 256 + t;
  if (n >= N) return;
  const float4* X4 = (const float4*)(X + (size_t)n * 128);
  float acc[32];
#pragma unroll
  for (int c = 0; c < 32; c++) acc[c] = 0.f;
  for (int k4 = 0; k4 < 32; k4++) {
    float4 x = X4[k4];
    const float4* w4 = (const float4*)(Wl + k4 * 128);
#pragma unroll
    for (int c4 = 0; c4 < 8; c4++) {
      float4 w0 = w4[c4], w1 = w4[8 + c4], w2 = w4[16 + c4], w3 = w4[24 + c4];
      float* A = acc + c4 * 4;
      A[0] = fmaf(x.x, w0.x, A[0]); A[1] = fmaf(x.x, w0.y, A[1]);
      A[2] = fmaf(x.x, w0.z, A[2]); A[3] = fmaf(x.x, w0.w, A[3]);
      A[0] = fmaf(x.y, w1.x, A[0]); A[1] = fmaf(x.y, w1.y, A[1]);
      A[2] = fmaf(x.y, w1.z, A[2]); A[3] = fmaf(x.y, w1.w, A[3]);
      A[0] = fmaf(x.z, w2.x, A[0]); A[1] = fmaf(x.z, w2.y, A[1]);
      A[2] = fmaf(x.z, w2.z, A[2]); A[3] = fmaf(x.z, w2.w, A[3]);
      A[0] = fmaf(x.w, w3.x, A[0]); A[1] = fmaf(x.w, w3.y, A[1]);
      A[2] = fmaf(x.w, w3.z, A[2]); A[3] = fmaf(x.w, w3.w, A[3]);
    }
  }
  float s0 = 0.f, d0 = 0.f, s1 = 0.f, d1 = 0.f;
#pragma unroll
  for (int c = 0; c < 16; c++) {
    s0 = fmaf(acc[c], Asl[c], s0);
    d0 = fmaf(acc[c], Adl[c], d0);
    s1 = fmaf(acc[16 + c], Asl[16 + c], s1);
    d1 = fmaf(acc[16 + c], Adl[16 + c], d1);
  }
  as1[n * 2] = s0; as1[n * 2 + 1] = s1;
  ad1[n * 2] = d0; ad1[n * 2 + 1] = d1;
#pragma unroll
  for (int j = 0; j < 4; j++) {
    uint4 u;
    u.x = (unsigned)f2h(acc[j * 8 + 0]) | ((unsigned)f2h(acc[j * 8 + 1]) << 16);
    u.y = (unsigned)f2h(acc[j * 8 + 2]) | ((unsigned)f2h(acc[j * 8 + 3]) << 16);
    u.z = (unsigned)f2h(acc[j * 8 + 4]) | ((unsigned)f2h(acc[j * 8 + 5]) << 16);
    u.w = (unsigned)f2h(acc[j * 8 + 6]) | ((unsigned)f2h(acc[j * 8 + 7]) << 16);
    h1h[(size_t)n * 4 + j] = u;
  }
}

// ------- fused agg1 (split-K=4, shfl) + x1 fp16 pack + attn2 dots -----------
// block = 16 nodes x 16 threads; r=(half 0-3, cq 0-3).
// r16: csr indices for group i+1 prefetched while group i's gathers fly.
__global__ __launch_bounds__(256, 8) void agg1_attn(
    const int* __restrict__ rp, const int* __restrict__ csr,
    const float* __restrict__ as, const float* __restrict__ ad,
    const uint4* __restrict__ h1h, const float* __restrict__ b1,
    const float* __restrict__ W2, const float* __restrict__ as2w,
    const float* __restrict__ ad2w, uint4* __restrict__ x1h,
    float* __restrict__ as2, float* __restrict__ ad2, int N) {
  __shared__ float val[32], vbl[32];
  int t = threadIdx.x;
  if (t < 32) {
    float a = 0.f, b = 0.f;
    for (int c = 0; c < 40; c++) {
      float w = W2[t * 40 + c];
      a = fmaf(w, as2w[c], a);
      b = fmaf(w, ad2w[c], b);
    }
    val[t] = a; vbl[t] = b;
  }
  __syncthreads();
  int nl = t >> 4, r = t & 15;
  int half = r >> 2, cq = r & 3;
  int h = cq >> 1;
  int n = blockIdx.x * 16 + nl;
  float acc[8] = {0, 0, 0, 0, 0, 0, 0, 0};
  float ssum = 0.f;
  if (n < N) {
    int p0 = rp[n], p1 = rp[n + 1];
    float adv = ad[n * 2 + h];
    int p = p0 + half;
    if (p + 12 < p1) {
      int sA = csr[p], sB = csr[p + 4], sC = csr[p + 8], sD = csr[p + 12];
      p += 16;
      while (true) {
        bool more = (p + 12 < p1);
        int nA = 0, nB = 0, nC = 0, nD = 0;
        if (more) { nA = csr[p]; nB = csr[p + 4]; nC = csr[p + 8]; nD = csr[p + 12]; }
        float eA = as[sA * 2 + h] + adv;
        float eB = as[sB * 2 + h] + adv;
        float eC = as[sC * 2 + h] + adv;
        float eD = as[sD * 2 + h] + adv;
        uint4 uA = h1h[(size_t)sA * 4 + cq];
        uint4 uB = h1h[(size_t)sB * 4 + cq];
        uint4 uC = h1h[(size_t)sC * 4 + cq];
        uint4 uD = h1h[(size_t)sD * 4 + cq];
        float xA = __expf(lrelu(eA));
        float xB = __expf(lrelu(eB));
        float xC = __expf(lrelu(eC));
        float xD = __expf(lrelu(eD));
        ssum += (xA + xB) + (xC + xD);
        acc8(acc, xA, uA);
        acc8(acc, xB, uB);
        acc8(acc, xC, uC);
        acc8(acc, xD, uD);
        if (!more) break;
        sA = nA; sB = nB; sC = nC; sD = nD;
        p += 16;
      }
    }
    // tail: <=3 edges, one parallel memory round (clamped + predicated)
    if (p < p1) {
      bool vB = p + 4 < p1, vC = p + 8 < p1;
      int pB = vB ? p + 4 : p;
      int pC = vC ? p + 8 : p;
      int sA = csr[p], sB = csr[pB], sC = csr[pC];
      float eA = as[sA * 2 + h] + adv;
      float eB = as[sB * 2 + h] + adv;
      float eC = as[sC * 2 + h] + adv;
      uint4 uA = h1h[(size_t)sA * 4 + cq];
      uint4 uB = h1h[(size_t)sB * 4 + cq];
      uint4 uC = h1h[(size_t)sC * 4 + cq];
      float xA = __expf(lrelu(eA));
      float xB = vB ? __expf(lrelu(eB)) : 0.f;
      float xC = vC ? __expf(lrelu(eC)) : 0.f;
      ssum += xA + xB + xC;
      acc8(acc, xA, uA);
      acc8(acc, xB, uB);
      acc8(acc, xC, uC);
    }
  }
  // combine 4 split-K halves (lanes r^4, r^8 within the 16-lane node group)
#pragma unroll
  for (int j = 0; j < 8; j++) acc[j] += __shfl_xor(acc[j], 4);
  ssum += __shfl_xor(ssum, 4);
#pragma unroll
  for (int j = 0; j < 8; j++) acc[j] += __shfl_xor(acc[j], 8);
  ssum += __shfl_xor(ssum, 8);
  if (n < N && half == 0) {
    float inv = 1.0f / (ssum + 1e-16f);
    float4 ba = ((const float4*)b1)[cq * 2];
    float4 bb = ((const float4*)b1)[cq * 2 + 1];
    float xv[8];
    xv[0] = fmaxf(fmaf(acc[0], inv, ba.x), 0.f);
    xv[1] = fmaxf(fmaf(acc[1], inv, ba.y), 0.f);
    xv[2] = fmaxf(fmaf(acc[2], inv, ba.z), 0.f);
    xv[3] = fmaxf(fmaf(acc[3], inv, ba.w), 0.f);
    xv[4] = fmaxf(fmaf(acc[4], inv, bb.x), 0.f);
    xv[5] = fmaxf(fmaf(acc[5], inv, bb.y), 0.f);
    xv[6] = fmaxf(fmaf(acc[6], inv, bb.z), 0.f);
    xv[7] = fmaxf(fmaf(acc[7], inv, bb.w), 0.f);
    uint4 u;
    u.x = (unsigned)f2h(xv[0]) | ((unsigned)f2h(xv[1]) << 16);
    u.y = (unsigned)f2h(xv[2]) | ((unsigned)f2h(xv[3]) << 16);
    u.z = (unsigned)f2h(xv[4]) | ((unsigned)f2h(xv[5]) << 16);
    u.w = (unsigned)f2h(xv[6]) | ((unsigned)f2h(xv[7]) << 16);
    x1h[(size_t)n * 4 + cq] = u;
    // attn2 scalars via 32-dots (channel slice cq*8..cq*8+7)
    int ch0 = cq * 8;
    float ss = 0.f, sd = 0.f;
#pragma unroll
    for (int j = 0; j < 8; j++) {
      ss = fmaf(xv[j], val[ch0 + j], ss);
      sd = fmaf(xv[j], vbl[ch0 + j], sd);
    }
    ss += __shfl_xor(ss, 1); sd += __shfl_xor(sd, 1);
    ss += __shfl_xor(ss, 2); sd += __shfl_xor(sd, 2);
    if (cq == 0) { as2[n] = ss; ad2[n] = sd; }
  }
}

// ------- fused softmax+agg over x1 (split-K=4, shfl) + node GEMM 32->40 -----
// block = 16 nodes x 16 threads; gather x1h rows (64B = ONE line per edge);
// epilogue: out[n] = W2^T * aggx[n] + b2 (per-node, LDS GEMM).
__global__ __launch_bounds__(256, 8) void agg2_gemm(
    const int* __restrict__ rp, const int* __restrict__ csr,
    const float* __restrict__ as, const float* __restrict__ ad,
    const uint4* __restrict__ x1h, const float* __restrict__ W2,
    const float* __restrict__ b2, float* __restrict__ outp, int N) {
  __shared__ float Wl[32 * 40];
  __shared__ float xt[16][33];
  __shared__ float hr[16][41];
  int t = threadIdx.x;
  for (int i = t; i < 320; i += 256)
    ((float4*)Wl)[i] = ((const float4*)W2)[i];
  int nl = t >> 4, r = t & 15;
  int half = r >> 2, cq = r & 3;
  int n = blockIdx.x * 16 + nl;
  float acc[8] = {0, 0, 0, 0, 0, 0, 0, 0};
  float ssum = 0.f;
  if (n < N) {
    int p0 = rp[n], p1 = rp[n + 1];
    float adv = ad[n];
    int p = p0 + half;
    if (p + 12 < p1) {
      int sA = csr[p], sB = csr[p + 4], sC = csr[p + 8], sD = csr[p + 12];
      p += 16;
      while (true) {
        bool more = (p + 12 < p1);
        int nA = 0, nB = 0, nC = 0, nD = 0;
        if (more) { nA = csr[p]; nB = csr[p + 4]; nC = csr[p + 8]; nD = csr[p + 12]; }
        float eA = as[sA] + adv;
        float eB = as[sB] + adv;
        float eC = as[sC] + adv;
        float eD = as[sD] + adv;
        uint4 uA = x1h[(size_t)sA * 4 + cq];
        uint4 uB = x1h[(size_t)sB * 4 + cq];
        uint4 uC = x1h[(size_t)sC * 4 + cq];
        uint4 uD = x1h[(size_t)sD * 4 + cq];
        float xA = __expf(lrelu(eA));
        float xB = __expf(lrelu(eB));
        float xC = __expf(lrelu(eC));
        float xD = __expf(lrelu(eD));
        ssum += (xA + xB) + (xC + xD);
        acc8(acc, xA, uA);
        acc8(acc, xB, uB);
        acc8(acc, xC, uC);
        acc8(acc, xD, uD);
        if (!more) break;
        sA = nA; sB = nB; sC = nC; sD = nD;
        p += 16;
      }
    }
    if (p < p1) {
      bool vB = p + 4 < p1, vC = p + 8 < p1;
      int pB = vB ? p + 4 : p;
      int pC = vC ? p + 8 : p;
      int sA = csr[p], sB = csr[pB], sC = csr[pC];
      float eA = as[sA] + adv;
      float eB = as[sB] + adv;
      float eC = as[sC] + adv;
      uint4 uA = x1h[(size_t)sA * 4 + cq];
      uint4 uB = x1h[(size_t)sB * 4 + cq];
      uint4 uC = x1h[(size_t)sC * 4 + cq];
      float xA = __expf(lrelu(eA));
      float xB = vB ? __expf(lrelu(eB)) : 0.f;
      float xC = vC ? __expf(lrelu(eC)) : 0.f;
      ssum += xA + xB + xC;
      acc8(acc, xA, uA);
      acc8(acc, xB, uB);
      acc8(acc, xC, uC);
    }
  }
#pragma unroll
  for (int j = 0; j < 8; j++) acc[j] += __shfl_xor(acc[j], 4);
  ssum += __shfl_xor(ssum, 4);
#pragma unroll
  for (int j = 0; j < 8; j++) acc[j] += __shfl_xor(acc[j], 8);
  ssum += __shfl_xor(ssum, 8);
  if (n < N && half == 0) {
    float inv = 1.0f / (ssum + 1e-16f);
    int ch0 = cq * 8;
#pragma unroll
    for (int j = 0; j < 8; j++) xt[nl][ch0 + j] = acc[j] * inv;
  }
  __syncthreads();  // covers Wl load + xt writes
  if (n < N && r < 8) {
    float a2[5] = {0, 0, 0, 0, 0};
    int cb = r * 5;
    for (int k = 0; k < 32; k++) {
      float x = xt[nl][k];
#pragma unroll
      for (int c = 0; c < 5; c++)
        a2[c] = fmaf(x, Wl[k * 40 + cb + c], a2[c]);
    }
#pragma unroll
    for (int c = 0; c < 5; c++) hr[nl][cb + c] = a2[c];
  }
  __syncthreads();
  if (n < N && r < 10) {
    const float* s = hr[nl] + r * 4;
    float4 bb = ((const float4*)b2)[r];
    float4 v;
    v.x = s[0] + bb.x; v.y = s[1] + bb.y;
    v.z = s[2] + bb.z; v.w = s[3] + bb.w;
    ((float4*)outp)[(size_t)n * 10 + r] = v;
  }
}

// ---------------- host launcher ----------------
extern "C" void kernel_launch(void* const* d_in, const int* in_sizes, int n_in,
                              void* d_out, int out_size, void* d_ws, size_t ws_size,
                              hipStream_t stream) {
  const float* X    = (const float*)d_in[0];
  const long long* eg64 = (const long long*)d_in[1];
  const int* eg32   = (const int*)d_in[1];
  const float* W1   = (const float*)d_in[3];
  const float* as1w = (const float*)d_in[4];
  const float* ad1w = (const float*)d_in[5];
  const float* b1   = (const float*)d_in[6];
  const float* W2   = (const float*)d_in[7];
  const float* as2w = (const float*)d_in[8];
  const float* ad2w = (const float*)d_in[9];
  const float* b2   = (const float*)d_in[10];
  float* out = (float*)d_out;

  const int N  = in_sizes[0] / 128;
  const int E  = in_sizes[1] / 2;
  const int EN = E + N;
  const int NB2 = (N + CB_SZ - 1) / CB_SZ;
  const int NWG = (EN + SC_CHUNK - 1) / SC_CHUNK;

  char* wbase = (char*)d_ws;
  size_t off = 0;
  auto alloc = [&](size_t bytes) -> void* {
    void* p = wbase + off;
    off += (bytes + 255) & ~(size_t)255;
    return p;
  };

  uint4* h1h = (uint4*)alloc((size_t)N * 64);        // fp16 h1, 64B rows
  // tmp (CSR build scratch) and x1h (fp16 x1 payload) are temporally
  // disjoint: tmp dies at bucket_rp_sort, x1h is born at agg1_attn.
  size_t usz = (size_t)EN * 4;
  if ((size_t)N * 64 > usz) usz = (size_t)N * 64;
  char* uni = (char*)alloc(usz);
  uint4* x1h = (uint4*)uni;
  int*   tmp = (int*)uni;
  float* as1 = (float*)alloc((size_t)N * 2 * 4);
  float* ad1 = (float*)alloc((size_t)N * 2 * 4);
  float* as2 = (float*)alloc((size_t)N * 4);
  float* ad2 = (float*)alloc((size_t)N * 4);
  int* rp     = (int*)alloc((size_t)(N + 1) * 4);
  int* bhist  = (int*)alloc(NBMAX * 4);
  int* bscan  = (int*)alloc((NBMAX + 1) * 4);
  int* gcur   = (int*)alloc(NBMAX * 4);
  int* csr    = (int*)alloc((size_t)EN * 4);
  (void)ws_size; (void)n_in; (void)out_size;

  const int gN = (N + 255) / 256;

  // CSR build: hist -> scan -> sorted scatter (run reservation) -> bucket sort
  hipMemsetAsync(bhist, 0, NBMAX * 4, stream);
  bucket_hist<<<1024, 256, 0, stream>>>(eg64, eg32, E, N, NB2, bhist);
  bucket_scan<<<1, NBMAX, 0, stream>>>(bhist, bscan, gcur, NB2, EN);
  chunk_scatter_sorted<<<NWG, 512, 0, stream>>>(eg64, eg32, E, N, NB2, gcur, tmp);
  bucket_rp_sort<<<NB2, 512, 0, stream>>>(bscan, tmp, rp, csr, N, EN);

  // Layer 1 projection
  gemm1f<<<gN, 256, 0, stream>>>(X, W1, as1w, ad1w, h1h, as1, ad1, N);
  // agg1 + x1 pack + attn2 dots (gemm2 folded out via linearity)
  agg1_attn<<<(N + 15) / 16, 256, 0, stream>>>(rp, csr, as1, ad1, h1h, b1,
                                               W2, as2w, ad2w, x1h, as2, ad2, N);
  // Layer 2: aggregate x1, then per-node GEMM 32->40 + bias -> output
  agg2_gemm<<<(N + 15) / 16, 256, 0, stream>>>(rp, csr, as2, ad2, x1h,
                                               W2, b2, out, N);
}